// Round 16
// baseline (57.398 us; speedup 1.0000x reference)
//
#include <hip/hip_runtime.h>
#include <hip/hip_bf16.h>

// HFOnlyAttn MFMA v13: 32 px per wave (two 16-px halves interleaved inside
// each head) -> wave count halves (4096), per-wave-constant latencies
// (weight loads, X round trip, addr setup) amortize over 2x work.
// State stays compact (~200 regs): Xf[3][2][2]=48 + yS[12]=48 + transients;
// launch_bounds(256,2) -> VGPR cap 256, no occupancy-chasing spill.
// Zero LDS. Weights from global packed table (d_ws).
// mfma_f32_16x16x32_bf16:  A: lane l -> row=l&15, k=(l>>4)*8+{0..7}
//                          B: lane l -> col=l&15, k=(l>>4)*8+{0..7}
//                          C: lane l -> col=l&15, row=(l>>4)*4+reg
// Relayout (v4/v10-verified): proj-B-frag(sp) lane(g,c) elem e = ych
// sp*32+g*8+e; holder lane ((g&1)*2+(e>>2))*16+c, head sp*2+(g>>1), reg e&3.
// Residual: channel b*64+m*16+g*4+j of pixel c lives in Xf[b][m>>1],
// element (g&1)*4+j, on lane ((m&1)*2+(g>>1))*16+c.

typedef __attribute__((ext_vector_type(8))) short bf16x8;
typedef __attribute__((ext_vector_type(4))) float f32x4;

constexpr int kHW = 16384;
constexpr int kC = 192;

__device__ __forceinline__ short f2bf(float f) {
  return (short)__bfloat16_as_ushort(__float2bfloat16(f));
}

// kernel0: pack Wqkv^T/Wproj^T A-fragments into ws (24 + 8 frags x 1024B).
__global__ void pack_weights(const float* __restrict__ Wqkv,
                             const float* __restrict__ Wproj,
                             unsigned char* __restrict__ wsc) {
  const int tid = threadIdx.x;
  const int wid = tid >> 6;
  const int l = tid & 63;
  const int c = l & 15;
  const int g = l >> 4;
  for (int f = wid; f < 24; f += 4) {
    const int m = f >> 1, s = f & 1;
    const int row = m * 16 + c;
    const int k0 = s * 32 + g * 8;
    bf16x8 wf;
#pragma unroll
    for (int j = 0; j < 8; ++j) wf[j] = f2bf(Wqkv[(k0 + j) * 192 + row]);
    *(bf16x8*)(wsc + f * 1024 + l * 16) = wf;
  }
  for (int f = wid; f < 8; f += 4) {
    const int m = f >> 1, s = f & 1;
    const int row = m * 16 + c;
    const int k0 = s * 32 + g * 8;
    bf16x8 wf;
#pragma unroll
    for (int j = 0; j < 8; ++j) wf[j] = f2bf(Wproj[(k0 + j) * 64 + row]);
    *(bf16x8*)(wsc + 24576 + f * 1024 + l * 16) = wf;
  }
}

// One head, BOTH pixel halves: q,k MFMAs -> 3x3 softmax -> v -> y packs.
template <int H>
__device__ __forceinline__ void head2(const bf16x8* __restrict__ wp, int l,
                                      const bf16x8 (&Xf)[3][2][2],
                                      uint2 (&pk)[3][2]) {
  const f32x4 zz = {0.f, 0.f, 0.f, 0.f};
  const bf16x8 qA0 = wp[(H * 2 + 0) * 64 + l];
  const bf16x8 qA1 = wp[(H * 2 + 1) * 64 + l];
  const bf16x8 kA0 = wp[((4 + H) * 2 + 0) * 64 + l];
  const bf16x8 kA1 = wp[((4 + H) * 2 + 1) * 64 + l];
  f32x4 q[3][2], k[3][2];
#pragma unroll
  for (int b = 0; b < 3; ++b)
#pragma unroll
    for (int u = 0; u < 2; ++u) {
      q[b][u] =
          __builtin_amdgcn_mfma_f32_16x16x32_bf16(qA0, Xf[b][0][u], zz, 0, 0, 0);
      q[b][u] = __builtin_amdgcn_mfma_f32_16x16x32_bf16(qA1, Xf[b][1][u],
                                                        q[b][u], 0, 0, 0);
      k[b][u] =
          __builtin_amdgcn_mfma_f32_16x16x32_bf16(kA0, Xf[b][0][u], zz, 0, 0, 0);
      k[b][u] = __builtin_amdgcn_mfma_f32_16x16x32_bf16(kA1, Xf[b][1][u],
                                                        k[b][u], 0, 0, 0);
    }
  const bf16x8 vA0 = wp[((8 + H) * 2 + 0) * 64 + l];
  const bf16x8 vA1 = wp[((8 + H) * 2 + 1) * 64 + l];
#pragma unroll
  for (int u = 0; u < 2; ++u) {
    float P[3][3];
#pragma unroll
    for (int r1 = 0; r1 < 3; ++r1) {
      float sc[3];
#pragma unroll
      for (int r2 = 0; r2 < 3; ++r2) {
        float d = q[r1][u][0] * k[r2][u][0] + q[r1][u][1] * k[r2][u][1] +
                  q[r1][u][2] * k[r2][u][2] + q[r1][u][3] * k[r2][u][3];
        d += __shfl_xor(d, 16);
        d += __shfl_xor(d, 32);
        sc[r2] = d * 0.25f;
      }
      const float mx = fmaxf(sc[0], fmaxf(sc[1], sc[2]));
      const float e0 = __expf(sc[0] - mx);
      const float e1 = __expf(sc[1] - mx);
      const float e2 = __expf(sc[2] - mx);
      const float inv = 1.f / (e0 + e1 + e2);
      P[r1][0] = e0 * inv;
      P[r1][1] = e1 * inv;
      P[r1][2] = e2 * inv;
    }
    f32x4 v[3];
#pragma unroll
    for (int b = 0; b < 3; ++b) {
      v[b] =
          __builtin_amdgcn_mfma_f32_16x16x32_bf16(vA0, Xf[b][0][u], zz, 0, 0, 0);
      v[b] = __builtin_amdgcn_mfma_f32_16x16x32_bf16(vA1, Xf[b][1][u], v[b], 0,
                                                     0, 0);
    }
#pragma unroll
    for (int r1 = 0; r1 < 3; ++r1) {
      f32x4 y = P[r1][0] * v[0] + P[r1][1] * v[1] + P[r1][2] * v[2];
      uint2 p;
      p.x = (unsigned)(unsigned short)f2bf(y[0]) |
            ((unsigned)(unsigned short)f2bf(y[1]) << 16);
      p.y = (unsigned)(unsigned short)f2bf(y[2]) |
            ((unsigned)(unsigned short)f2bf(y[3]) << 16);
      pk[r1][u] = p;
    }
  }
}

// Build proj-B-frag for K-step sp from the packs of heads (2sp, 2sp+1).
__device__ __forceinline__ bf16x8 build_frag(uint2 pkA, uint2 pkB, int srcA,
                                             bool hi) {
  uint2 a0, a1, b0, b1;
  a0.x = (unsigned)__shfl((int)pkA.x, srcA, 64);
  a0.y = (unsigned)__shfl((int)pkA.y, srcA, 64);
  a1.x = (unsigned)__shfl((int)pkB.x, srcA, 64);
  a1.y = (unsigned)__shfl((int)pkB.y, srcA, 64);
  const int srcB = srcA + 16;
  b0.x = (unsigned)__shfl((int)pkA.x, srcB, 64);
  b0.y = (unsigned)__shfl((int)pkA.y, srcB, 64);
  b1.x = (unsigned)__shfl((int)pkB.x, srcB, 64);
  b1.y = (unsigned)__shfl((int)pkB.y, srcB, 64);
  const uint2 lo = hi ? a1 : a0;
  const uint2 hi2 = hi ? b1 : b0;
  union {
    unsigned u[4];
    bf16x8 v;
  } r;
  r.u[0] = lo.x;
  r.u[1] = lo.y;
  r.u[2] = hi2.x;
  r.u[3] = hi2.y;
  return r.v;
}

__global__ __launch_bounds__(256, 2) void hfattn_mfma13(
    const float* __restrict__ hf,
    const unsigned char* __restrict__ wfr,  // packed weight frags (32KB)
    const float* __restrict__ bproj,
    const float* __restrict__ rscale,
    float* __restrict__ out) {
  const int tid = threadIdx.x;
  const int wid = tid >> 6;
  const int l = tid & 63;
  const int c = l & 15;  // MFMA col (pixel slot)
  const int g = l >> 4;  // 4-lane group

  const f32x4 zz = {0.f, 0.f, 0.f, 0.f};
  const bf16x8* const wp = (const bf16x8*)wfr;

  const int pxB0 = blockIdx.x * 128 + wid * 32;  // 1024 blocks x 128 px
  const int b8 = pxB0 >> 14;
  const int blkBase = b8 * (kC * kHW);
  const int hw = (pxB0 & (kHW - 1)) + c;
  const float* __restrict__ hfp0 = hf + blkBase + hw;
  float* __restrict__ outp0 = out + blkBase + hw;

  const float rv = rscale[0];

  // ---------- issue ALL 96 X loads (both halves), fence, convert ----------
  float xr0[3][2][8], xr1[3][2][8];
#pragma unroll
  for (int b = 0; b < 3; ++b)
#pragma unroll
    for (int s = 0; s < 2; ++s)
#pragma unroll
      for (int j = 0; j < 8; ++j) {
        const int off = (b * 64 + s * 32 + g * 8 + j) * kHW;
        xr0[b][s][j] = hfp0[off];
        xr1[b][s][j] = hfp0[off + 16];
      }
  __builtin_amdgcn_sched_barrier(0);  // all loads issue before any convert

  bf16x8 Xf[3][2][2];
#pragma unroll
  for (int b = 0; b < 3; ++b)
#pragma unroll
    for (int s = 0; s < 2; ++s) {
      bf16x8 x0, x1;
#pragma unroll
      for (int j = 0; j < 8; ++j) {
        x0[j] = f2bf(xr0[b][s][j]);
        x1[j] = f2bf(xr1[b][s][j]);
      }
      Xf[b][s][0] = x0;
      Xf[b][s][1] = x1;
    }

  // ---------- heads + in-register y relayout (both halves) ----------
  const int srcA = ((g & 1) * 2) * 16 + c;
  const bool hi = (g >> 1) & 1;

  uint2 pkA[3][2], pkB[3][2];
  bf16x8 yS0[3][2], yS1[3][2];

  head2<0>(wp, l, Xf, pkA);
  __builtin_amdgcn_sched_barrier(0);
  head2<1>(wp, l, Xf, pkB);
  __builtin_amdgcn_sched_barrier(0);
#pragma unroll
  for (int b = 0; b < 3; ++b)
#pragma unroll
    for (int u = 0; u < 2; ++u)
      yS0[b][u] = build_frag(pkA[b][u], pkB[b][u], srcA, hi);
  __builtin_amdgcn_sched_barrier(0);
  head2<2>(wp, l, Xf, pkA);
  __builtin_amdgcn_sched_barrier(0);
  head2<3>(wp, l, Xf, pkB);
  __builtin_amdgcn_sched_barrier(0);
#pragma unroll
  for (int b = 0; b < 3; ++b)
#pragma unroll
    for (int u = 0; u < 2; ++u)
      yS1[b][u] = build_frag(pkA[b][u], pkB[b][u], srcA, hi);

  // ---------- epilogue: proj + residual-from-Xf, both halves ----------
  float bias_[4][4];
#pragma unroll
  for (int m = 0; m < 4; ++m) {
    const float4 bj = *(const float4*)(bproj + m * 16 + g * 4);
    bias_[m][0] = bj.x;
    bias_[m][1] = bj.y;
    bias_[m][2] = bj.z;
    bias_[m][3] = bj.w;
  }

#pragma unroll
  for (int b = 0; b < 3; ++b) {
#pragma unroll
    for (int m = 0; m < 4; ++m) {
      const bf16x8 pA0 = wp[(24 + m * 2 + 0) * 64 + l];
      const bf16x8 pA1 = wp[(24 + m * 2 + 1) * 64 + l];
      const int hl = ((m & 1) * 2 + (g >> 1)) * 16 + c;
#pragma unroll
      for (int u = 0; u < 2; ++u) {
        f32x4 o = __builtin_amdgcn_mfma_f32_16x16x32_bf16(pA0, yS0[b][u], zz, 0,
                                                          0, 0);
        o = __builtin_amdgcn_mfma_f32_16x16x32_bf16(pA1, yS1[b][u], o, 0, 0, 0);

        // residual from Xf via wave shuffles (all transient)
        union {
          bf16x8 v;
          unsigned w[4];
        } su;
        su.v = Xf[b][m >> 1][u];
        const unsigned w0 = (unsigned)__shfl((int)su.w[0], hl, 64);
        const unsigned w1 = (unsigned)__shfl((int)su.w[1], hl, 64);
        const unsigned w2 = (unsigned)__shfl((int)su.w[2], hl, 64);
        const unsigned w3 = (unsigned)__shfl((int)su.w[3], hl, 64);
        const unsigned lo = (g & 1) ? w2 : w0;   // channels j=0,1
        const unsigned hi2 = (g & 1) ? w3 : w1;  // channels j=2,3
        float res[4];
        res[0] = __uint_as_float(lo << 16);
        res[1] = __uint_as_float(lo & 0xffff0000u);
        res[2] = __uint_as_float(hi2 << 16);
        res[3] = __uint_as_float(hi2 & 0xffff0000u);

#pragma unroll
        for (int j = 0; j < 4; ++j) {
          outp0[(b * 64 + m * 16 + g * 4 + j) * kHW + u * 16] =
              fmaf(rv, o[j] + bias_[m][j], res[j]);
        }
      }
    }
  }
}

extern "C" void kernel_launch(void* const* d_in, const int* in_sizes, int n_in,
                              void* d_out, int out_size, void* d_ws,
                              size_t ws_size, hipStream_t stream) {
  const float* hf = (const float*)d_in[0];
  const float* Wqkv = (const float*)d_in[1];
  const float* Wproj = (const float*)d_in[2];
  const float* bproj = (const float*)d_in[3];
  const float* rscale = (const float*)d_in[4];
  float* out = (float*)d_out;
  unsigned char* wsc = (unsigned char*)d_ws;

  hipLaunchKernelGGL(pack_weights, dim3(1), dim3(256), 0, stream, Wqkv, Wproj,
                     wsc);

  const int npix = in_sizes[0] / kC;  // 131072
  const int nblocks = npix / 128;     // 1024
  hipLaunchKernelGGL(hfattn_mfma13, dim3(nblocks), dim3(256), 0, stream, hf,
                     wsc, bproj, rscale, out);
}